// Round 1
// 69.161 us; speedup vs baseline: 1.0252x; 1.0252x over previous
//
#include <hip/hip_runtime.h>

// Problem constants (from reference setup_inputs): B=4096, L=128, D=64, V=1000
#define LSEQ 128
#define DIM  64
#define TAIL 16    // w[l]=e^(l-128); dropping l<112 leaves error <= e^-16*2*max|G| ~ 1e-4

// Single fused kernel. 2 rows per block, 4 waves; each wave owns one (row, sel)
// output end-to-end. No LDS, no __syncthreads, no workspace, no G table.
//
// Math: feat[d] = sum_k W2[k][d] * S_k,
//       S_k    = sum_{l in tail} w_l * ( relu(c0_l*W1_k + b1_k) + relu(c1_l*W1_k + b1_k) )
// c0_l/c1_l are wave-uniform (ballot counts), so lane plays role k during the
// ballot loop (S in-register), then role d during a 64-step readlane matvec.
__global__ __launch_bounds__(256) void gae_fused_kernel(
        const int* __restrict__ src_ids,
        const int* __restrict__ dst_ids,
        const float* __restrict__ W1,
        const float* __restrict__ b1,
        const float* __restrict__ W2,
        const float* __restrict__ b2,
        float* __restrict__ out,
        int B) {
    const int lane = threadIdx.x & 63;
    const int g    = threadIdx.x >> 6;
    const int sel  = g & 1;                      // 0 = src_feat, 1 = dst_feat
    const int row  = blockIdx.x * 2 + (g >> 1);
    if (row >= B) return;

    // lane plays role k here: per-lane MLP params (256B loads, L1-hot)
    const float w1k = W1[lane];
    const float b1k = b1[lane];

    const int* __restrict__ sp = src_ids + (size_t)row * LSEQ;
    const int* __restrict__ dp = dst_ids + (size_t)row * LSEQ;
    // redundant across the 2 waves of a row -> L1 hits
    const int s_lo = sp[lane];
    const int s_hi = sp[lane + 64];
    const int d_lo = dp[lane];
    const int d_hi = dp[lane + 64];
    const int my_hi = sel ? d_hi : s_hi;         // tail positions 112..127 live here

    float w = 1.12535174719259115e-7f;           // e^-16, running product (const-folds)
    float S = 0.0f;                              // S_k accumulator, k = lane
#pragma unroll
    for (int i = 0; i < TAIL; ++i) {
        const int l = LSEQ - TAIL + i;
        // wave-uniform tail id (readlane -> SGPR broadcast, lane index is literal)
        const int v = __builtin_amdgcn_readlane(my_hi, l - 64);
        // count of v across all 128 positions of each list (wave-uniform scalars)
        int c0 = __popcll(__ballot(s_lo == v)) + __popcll(__ballot(s_hi == v));
        int c1 = __popcll(__ballot(d_lo == v)) + __popcll(__ballot(d_hi == v));
        if (v == 0) { c0 = 0; c1 = 0; }          // padding: count -> 0 (relu(b1) survives)
        const float r0 = fmaxf(fmaf((float)c0, w1k, b1k), 0.0f);
        const float r1 = fmaxf(fmaf((float)c1, w1k, b1k), 0.0f);
        S = fmaf(w, r0 + r1, S);
        w *= 2.71828182845904523f;
    }

    // lane plays role d now: feat[d] = sum_k S_k * W2[k][d].
    // readlane(k) broadcasts S_k via SGPR; W2 row reads are 256B contiguous, L1-hot.
    float acc0 = 0.0f, acc1 = 0.0f;
#pragma unroll
    for (int k = 0; k < DIM; k += 2) {
        const float sk0 = __uint_as_float(__builtin_amdgcn_readlane(__float_as_uint(S), k));
        const float sk1 = __uint_as_float(__builtin_amdgcn_readlane(__float_as_uint(S), k + 1));
        acc0 = fmaf(sk0, W2[k * DIM + lane], acc0);
        acc1 = fmaf(sk1, W2[(k + 1) * DIM + lane], acc1);
    }

    // 1 / sum_{l=0..127} e^(l-128) == e-1 in fp32
    const float invW = 1.71828182845904523f;
    out[(size_t)sel * B * DIM + (size_t)row * DIM + lane] =
        (acc0 + acc1) * invW + 2.0f * b2[lane];
}

extern "C" void kernel_launch(void* const* d_in, const int* in_sizes, int n_in,
                              void* d_out, int out_size, void* d_ws, size_t ws_size,
                              hipStream_t stream) {
    const int*   src_ids = (const int*)d_in[0];
    const int*   dst_ids = (const int*)d_in[1];
    const float* W1      = (const float*)d_in[2];
    const float* b1      = (const float*)d_in[3];
    const float* W2      = (const float*)d_in[4];
    const float* b2      = (const float*)d_in[5];
    float*       out     = (float*)d_out;
    (void)d_ws; (void)ws_size;                   // workspace no longer used

    const int B = in_sizes[0] / LSEQ;

    gae_fused_kernel<<<(B + 1) / 2, 256, 0, stream>>>(
        src_ids, dst_ids, W1, b1, W2, b2, out, B);
}